// Round 7
// baseline (924.611 us; speedup 1.0000x reference)
//
#include <hip/hip_runtime.h>
#include <hip/hip_cooperative_groups.h>
#include <stdint.h>
#include <math.h>

namespace cg = cooperative_groups;

// ---------------------------------------------------------------------------
// kWTA: threshold = K-th largest of N fp32; out[i] = in[i] < thr ? 0 : in[i]
//
// ONE cooperative kernel (R6 lesson: 7 dispatches cost ~200us in gaps).
// Phases (grid.sync between):
//  0 zero ws control region
//  1 sample 1M elems -> 12-bit global hist        (unconditional LDS atomics:
//    R1/R6 evidence: those are fast; conditional ones are 2x slow)
//  2 block0: pick cut bin s.t. LCB(true tail count) >= K (~4.2K candidates)
//  3 THE full pass: out = key>=cut ? v : 0 (NT stores, unroll-4) + ballot-
//    compacted (key,idx) into per-wave private regions. Zero atomics in loop.
//  4 block0: gather candidate keys from regions -> LDS, exact 32-bit radix
//    select -> threshold, zero the losers (winners already written).
//  5 uniform early-return unless fallback flag; else exact gated FB chain.
// ---------------------------------------------------------------------------

#define TPB 256
#define MAXNB 1024
#define NWAVES_MAX (MAXNB * TPB / 64)  // 4096
#define CAPW 64                        // per-wave region capacity

// ws word offsets
#define SH_OFF   0      // sample hist 4096
#define WCNT_OFF 4096   // per-wave counts 4096
#define FBH_OFF  8192   // fallback hist 4096
#define CTRL     12288  // 16 control words
#define ZERO_WORDS 12304
#define REGK_OFF 12304
#define REGWORDS (NWAVES_MAX * CAPW)   // 262144
#define FBPK_OFF (REGK_OFF + 2 * REGWORDS)  // 536592

// ctrl indices
#define C_FLAG 0   // overflow flag (phase 3/4)
#define C_CUT  1   // 12-bit cut bin
#define C_THR  2   // threshold key (debug)
#define C_FB2  3   // final fallback decision
#define C_SEL  4   // fb: selected 12-bit bin
#define C_WANT 5   // fb: rank within bin
#define C_FBN  6   // fb pair count

__device__ __forceinline__ uint32_t f2key(float x) {
  uint32_t u = __float_as_uint(x);
  return (u & 0x80000000u) ? ~u : (u | 0x80000000u);  // larger key <=> larger float
}
__device__ __forceinline__ float key2f(uint32_t k) {
  uint32_t u = (k & 0x80000000u) ? (k & 0x7fffffffu) : ~k;
  return __uint_as_float(u);
}

__device__ __forceinline__ void apply1(float4 v, int i, uint32_t cutK,
                                       float* outp, uint32_t* keysR,
                                       uint32_t* idxR, uint32_t rbase,
                                       uint32_t& wcount, uint64_t lt) {
  uint32_t k0 = f2key(v.x), k1 = f2key(v.y), k2 = f2key(v.z), k3 = f2key(v.w);
  bool q0 = k0 >= cutK, q1 = k1 >= cutK, q2 = k2 >= cutK, q3 = k3 >= cutK;
  float* o = outp + 4 * (size_t)i;
  __builtin_nontemporal_store(q0 ? v.x : 0.0f, o);
  __builtin_nontemporal_store(q1 ? v.y : 0.0f, o + 1);
  __builtin_nontemporal_store(q2 ? v.z : 0.0f, o + 2);
  __builtin_nontemporal_store(q3 ? v.w : 0.0f, o + 3);
  if (__ballot(q0 | q1 | q2 | q3)) {  // rare: ~3% of wave-iters
    uint32_t base = 4u * (uint32_t)i;
    uint64_t m0 = __ballot(q0);
    if (q0) { uint32_t p = wcount + (uint32_t)__popcll(m0 & lt); if (p < CAPW) { keysR[rbase + p] = k0; idxR[rbase + p] = base; } }
    wcount += (uint32_t)__popcll(m0);
    uint64_t m1 = __ballot(q1);
    if (q1) { uint32_t p = wcount + (uint32_t)__popcll(m1 & lt); if (p < CAPW) { keysR[rbase + p] = k1; idxR[rbase + p] = base + 1u; } }
    wcount += (uint32_t)__popcll(m1);
    uint64_t m2 = __ballot(q2);
    if (q2) { uint32_t p = wcount + (uint32_t)__popcll(m2 & lt); if (p < CAPW) { keysR[rbase + p] = k2; idxR[rbase + p] = base + 2u; } }
    wcount += (uint32_t)__popcll(m2);
    uint64_t m3 = __ballot(q3);
    if (q3) { uint32_t p = wcount + (uint32_t)__popcll(m3 & lt); if (p < CAPW) { keysR[rbase + p] = k3; idxR[rbase + p] = base + 3u; } }
    wcount += (uint32_t)__popcll(m3);
  }
}

__global__ void __launch_bounds__(TPB, 4)
k_kwta(const float4* __restrict__ in4, float4* __restrict__ out4,
       int n4, int ntail, const float* __restrict__ in_s,
       float* __restrict__ out_s, const int* __restrict__ kptr, uint32_t n,
       uint32_t* __restrict__ ws, uint32_t* __restrict__ keysR,
       uint32_t* __restrict__ idxR, uint32_t* __restrict__ keysF,
       uint32_t* __restrict__ idxF, uint32_t fbcap) {
  cg::grid_group grid = cg::this_grid();
  __shared__ uint32_t shb[8192];
  __shared__ uint32_t chunk[256];
  __shared__ uint32_t pre[256];
  __shared__ uint32_t red[4];
  __shared__ uint32_t s_a, s_b;
  const int t = threadIdx.x;
  const int b = blockIdx.x;
  const int nb = gridDim.x;
  const int T = nb * TPB;
  const int gtid = b * TPB + t;
  const int lane = t & 63;
  const uint64_t lt = (1ULL << lane) - 1ULL;

  // ---- Phase 0: zero control region ----
  for (int i = gtid; i < ZERO_WORDS; i += T) ws[i] = 0u;
  grid.sync();

  // ---- Phase 1: sample T*4 elements -> 12-bit hist ----
  for (int i = t; i < 4096; i += TPB) shb[i] = 0u;
  __syncthreads();
  if (n4 >= T) {
    float4 v = in4[b * (n4 / nb) + t];
    atomicAdd(&shb[f2key(v.x) >> 20], 1u);
    atomicAdd(&shb[f2key(v.y) >> 20], 1u);
    atomicAdd(&shb[f2key(v.z) >> 20], 1u);
    atomicAdd(&shb[f2key(v.w) >> 20], 1u);
  }
  __syncthreads();
  for (int i = t; i < 4096; i += TPB) {
    uint32_t c = shb[i];
    if (c) atomicAdd(&ws[SH_OFF + i], c);
  }
  grid.sync();

  // ---- Phase 2: block0 picks cut ----
  if (b == 0) {
    for (int i = t; i < 4096; i += TPB) shb[i] = ws[SH_OFF + i];
    __syncthreads();
    uint32_t s = 0;
#pragma unroll
    for (int i = 0; i < 16; i++) s += shb[t * 16 + i];
    chunk[t] = s;
    __syncthreads();
    if (t == 0) {
      int kv = kptr[0];
      uint32_t K = kv < 1 ? 1u : (uint32_t)kv;
      if (K > n) K = n;
      double M = (double)T * 4.0;
      double A = (double)K * M / (double)(n ? n : 1u);
      double x = 4.0 + sqrt(A + 24.0);  // LCB: s - 8*sqrt(s) - 8 >= A
      uint32_t smin = (uint32_t)(x * x) + 1u;
      if (smin < 64u) smin = 64u;
      uint32_t acc = 0, cut = 0;
      for (int c = 255; c >= 0; c--) {
        if (acc + chunk[c] >= smin) {
          for (int b2 = c * 16 + 15; b2 >= c * 16; b2--) {
            acc += shb[b2];
            if (acc >= smin) { cut = (uint32_t)b2; break; }
          }
          break;
        }
        acc += chunk[c];
      }
      ws[CTRL + C_CUT] = cut;  // 0 if unreachable -> everything qualifies -> FB
    }
  }
  grid.sync();

  // ---- Phase 3: THE full pass (apply + ballot-compacted gather) ----
  {
    const uint32_t cutK = ws[CTRL + C_CUT] << 20;
    const int wave = gtid >> 6;
    const uint32_t rbase = (uint32_t)wave * CAPW;
    uint32_t wcount = 0;
    int i = gtid;
    for (; i + 3 * T < n4; i += 4 * T) {
      float4 v0 = in4[i];
      float4 v1 = in4[i + T];
      float4 v2 = in4[i + 2 * T];
      float4 v3 = in4[i + 3 * T];
      apply1(v0, i, cutK, (float*)out4, keysR, idxR, rbase, wcount, lt);
      apply1(v1, i + T, cutK, (float*)out4, keysR, idxR, rbase, wcount, lt);
      apply1(v2, i + 2 * T, cutK, (float*)out4, keysR, idxR, rbase, wcount, lt);
      apply1(v3, i + 3 * T, cutK, (float*)out4, keysR, idxR, rbase, wcount, lt);
    }
    for (; i < n4; i += T) {
      float4 v = in4[i];
      apply1(v, i, cutK, (float*)out4, keysR, idxR, rbase, wcount, lt);
    }
    if (b == 0 && (t >> 6) == 0) {  // scalar tail, wave 0
      int j = n4 * 4 + lane;
      bool q = false;
      uint32_t kk = 0;
      if (lane < ntail) {
        float x = in_s[j];
        kk = f2key(x);
        q = kk >= cutK;
        out_s[j] = q ? x : 0.0f;
      }
      uint64_t mq = __ballot(q);
      if (q) { uint32_t p = wcount + (uint32_t)__popcll(mq & lt); if (p < CAPW) { keysR[rbase + p] = kk; idxR[rbase + p] = (uint32_t)j; } }
      wcount += (uint32_t)__popcll(mq);
    }
    if (lane == 0) {
      ws[WCNT_OFF + wave] = wcount;
      if (wcount > CAPW) atomicOr(&ws[CTRL + C_FLAG], 1u);
    }
  }
  grid.sync();

  // ---- Phase 4: block0 selects threshold + zeroes losers ----
  if (b == 0) {
    int kv = kptr[0];
    uint32_t K = kv < 1 ? 1u : (uint32_t)kv;
    if (K > n) K = n;
    uint32_t csum = 0;
    for (int r = t * 16; r < t * 16 + 16; r++) {
      uint32_t c = ws[WCNT_OFF + r];
      csum += (c > CAPW ? CAPW : c);
    }
    chunk[t] = csum;
    __syncthreads();
    if (t == 0) {
      uint32_t acc = 0;
      for (int j = 0; j < 256; j++) { uint32_t c = chunk[j]; pre[j] = acc; acc += c; }
      s_a = acc;
    }
    __syncthreads();
    uint32_t tot = s_a;
    bool dofb = (ws[CTRL + C_FLAG] != 0u) || (tot < K) || (tot > 8192u);
    __syncthreads();
    if (!dofb) {
      uint32_t off = pre[t];
      for (int r = t * 16; r < t * 16 + 16; r++) {
        uint32_t c = ws[WCNT_OFF + r];  // <= CAPW (else dofb)
        for (uint32_t j = 0; j < c; j++) shb[off + j] = keysR[(uint32_t)r * CAPW + j];
        off += c;
      }
      __syncthreads();
      uint32_t p = 0, want = K;
      for (int bit = 31; bit >= 0; bit--) {
        uint32_t test = p | (1u << bit), hi = test >> bit, cnt = 0;
        for (uint32_t ii = t; ii < tot; ii += TPB) cnt += ((shb[ii] >> bit) == hi) ? 1u : 0u;
        for (int o2 = 32; o2; o2 >>= 1) cnt += __shfl_down((int)cnt, o2);
        if (lane == 0) red[t >> 6] = cnt;
        __syncthreads();
        if (t == 0) {
          uint32_t tc = red[0] + red[1] + red[2] + red[3];
          if (tc >= want) p = test; else want -= tc;
          s_a = p; s_b = want;
        }
        __syncthreads();
        p = s_a; want = s_b;
      }
      // zero losers (winners were already written in phase 3)
      for (int r = t * 16; r < t * 16 + 16; r++) {
        uint32_t c = ws[WCNT_OFF + r];
        for (uint32_t j = 0; j < c; j++) {
          uint32_t kk = keysR[(uint32_t)r * CAPW + j];
          if (kk < p) out_s[idxR[(uint32_t)r * CAPW + j]] = 0.0f;
        }
      }
      if (t == 0) ws[CTRL + C_THR] = p;
    }
    if (t == 0) ws[CTRL + C_FB2] = dofb ? 1u : 0u;
  }
  grid.sync();

  // ---- Phase 5: uniform early exit on happy path ----
  if (ws[CTRL + C_FB2] == 0u) return;

  // ======================= FALLBACK (exact, gated) =========================
  // FB-A: full 12-bit hist (unconditional LDS atomics)
  for (int i = t; i < 4096; i += TPB) shb[i] = 0u;
  __syncthreads();
  for (int i = gtid; i < n4; i += T) {
    float4 v = in4[i];
    atomicAdd(&shb[f2key(v.x) >> 20], 1u);
    atomicAdd(&shb[f2key(v.y) >> 20], 1u);
    atomicAdd(&shb[f2key(v.z) >> 20], 1u);
    atomicAdd(&shb[f2key(v.w) >> 20], 1u);
  }
  if (b == 0 && t < ntail) atomicAdd(&shb[f2key(in_s[n4 * 4 + t]) >> 20], 1u);
  __syncthreads();
  for (int i = t; i < 4096; i += TPB) {
    uint32_t c = shb[i];
    if (c) atomicAdd(&ws[FBH_OFF + i], c);
  }
  grid.sync();

  // FB-B: block0 selects bin + rank
  if (b == 0) {
    for (int i = t; i < 4096; i += TPB) shb[i] = ws[FBH_OFF + i];
    __syncthreads();
    uint32_t s = 0;
#pragma unroll
    for (int i = 0; i < 16; i++) s += shb[t * 16 + i];
    chunk[t] = s;
    __syncthreads();
    if (t == 0) {
      int kv = kptr[0];
      uint32_t K = kv < 1 ? 1u : (uint32_t)kv;
      if (K > n) K = n;
      uint32_t above = 0;
      int sel = 0;
      for (int c = 255; c >= 0; c--) {
        if (above + chunk[c] >= K) { sel = c; break; }
        above += chunk[c];
      }
      int bsel = sel * 16;
      for (int b2 = sel * 16 + 15; b2 >= sel * 16; b2--) {
        uint32_t c = shb[b2];
        if (above + c >= K) { bsel = b2; break; }
        above += c;
      }
      ws[CTRL + C_SEL] = (uint32_t)bsel;
      ws[CTRL + C_WANT] = K - above;
    }
  }
  grid.sync();

  // FB-C: re-apply (>sel keep, ==sel 0 + record, <sel 0)
  {
    uint32_t sel = ws[CTRL + C_SEL];
    for (int i = gtid; i < n4; i += T) {
      float4 v = in4[i];
      uint32_t k0 = f2key(v.x), k1 = f2key(v.y), k2 = f2key(v.z), k3 = f2key(v.w);
      uint32_t b0 = k0 >> 20, b1 = k1 >> 20, b2 = k2 >> 20, b3 = k3 >> 20;
      float4 r;
      r.x = (b0 > sel) ? v.x : 0.0f;
      r.y = (b1 > sel) ? v.y : 0.0f;
      r.z = (b2 > sel) ? v.z : 0.0f;
      r.w = (b3 > sel) ? v.w : 0.0f;
      out4[i] = r;
      uint32_t base = 4u * (uint32_t)i;
      if (b0 == sel) { uint32_t p = atomicAdd(&ws[CTRL + C_FBN], 1u); if (p < fbcap) { keysF[p] = k0; idxF[p] = base; } }
      if (b1 == sel) { uint32_t p = atomicAdd(&ws[CTRL + C_FBN], 1u); if (p < fbcap) { keysF[p] = k1; idxF[p] = base + 1u; } }
      if (b2 == sel) { uint32_t p = atomicAdd(&ws[CTRL + C_FBN], 1u); if (p < fbcap) { keysF[p] = k2; idxF[p] = base + 2u; } }
      if (b3 == sel) { uint32_t p = atomicAdd(&ws[CTRL + C_FBN], 1u); if (p < fbcap) { keysF[p] = k3; idxF[p] = base + 3u; } }
    }
    if (b == 0 && t < ntail) {
      int j = n4 * 4 + t;
      float x = in_s[j];
      uint32_t kk = f2key(x);
      uint32_t bb = kk >> 20;
      out_s[j] = (bb > sel) ? x : 0.0f;
      if (bb == sel) { uint32_t p = atomicAdd(&ws[CTRL + C_FBN], 1u); if (p < fbcap) { keysF[p] = kk; idxF[p] = (uint32_t)j; } }
    }
  }
  grid.sync();

  // FB-D: block0 exact in-bin select + restore winners
  if (b == 0) {
    uint32_t sel = ws[CTRL + C_SEL];
    uint32_t want = ws[CTRL + C_WANT];
    uint32_t m = ws[CTRL + C_FBN];
    bool slow = m > fbcap;
    uint32_t p = sel << 20;
    if (!slow) {
      bool useLds = m <= 8192u;
      if (useLds) for (uint32_t ii = t; ii < m; ii += TPB) shb[ii] = keysF[ii];
      __syncthreads();
      for (int bit = 19; bit >= 0; bit--) {
        uint32_t test = p | (1u << bit), hi = test >> bit, cnt = 0;
        for (uint32_t ii = t; ii < m; ii += TPB) {
          uint32_t kk = useLds ? shb[ii] : keysF[ii];
          cnt += ((kk >> bit) == hi) ? 1u : 0u;
        }
        for (int o2 = 32; o2; o2 >>= 1) cnt += __shfl_down((int)cnt, o2);
        if (lane == 0) red[t >> 6] = cnt;
        __syncthreads();
        if (t == 0) {
          uint32_t tc = red[0] + red[1] + red[2] + red[3];
          if (tc >= want) p = test; else want -= tc;
          s_a = p; s_b = want;
        }
        __syncthreads();
        p = s_a; want = s_b;
      }
      for (uint32_t ii = t; ii < m; ii += TPB) {
        uint32_t kk = useLds ? shb[ii] : keysF[ii];
        if (kk >= p) out_s[idxF[ii]] = key2f(kk);
      }
    } else {  // exact-but-slow input scan (never expected)
      for (int bit = 19; bit >= 0; bit--) {
        uint32_t test = p | (1u << bit), hi = test >> bit, cnt = 0;
        for (uint32_t ii = t; ii < n; ii += TPB) {
          uint32_t kk = f2key(in_s[ii]);
          if ((kk >> 20) == sel) cnt += ((kk >> bit) == hi) ? 1u : 0u;
        }
        for (int o2 = 32; o2; o2 >>= 1) cnt += __shfl_down((int)cnt, o2);
        if (lane == 0) red[t >> 6] = cnt;
        __syncthreads();
        if (t == 0) {
          uint32_t tc = red[0] + red[1] + red[2] + red[3];
          if (tc >= want) p = test; else want -= tc;
          s_a = p; s_b = want;
        }
        __syncthreads();
        p = s_a; want = s_b;
      }
      for (uint32_t ii = t; ii < n; ii += TPB) {
        uint32_t kk = f2key(in_s[ii]);
        if ((kk >> 20) == sel && kk >= p) out_s[ii] = in_s[ii];
      }
    }
    if (t == 0) ws[CTRL + C_THR] = p;
  }
}

extern "C" void kernel_launch(void* const* d_in, const int* in_sizes, int n_in,
                              void* d_out, int out_size, void* d_ws, size_t ws_size,
                              hipStream_t stream) {
  const float* in = (const float*)d_in[0];
  const int* kptr = (const int*)d_in[1];
  float* out = (float*)d_out;
  int n = in_sizes[0];
  int n4 = n >> 2;
  int ntail = n & 3;

  uint32_t* ws = (uint32_t*)d_ws;
  int64_t ws_words = (int64_t)(ws_size / 4);
  uint32_t* keysR = ws + REGK_OFF;
  uint32_t* idxR = keysR + REGWORDS;
  int64_t rem = ws_words - (int64_t)FBPK_OFF;
  uint32_t fbcap = rem > 1 ? (uint32_t)(rem / 2) : 0u;
  uint32_t* keysF = ws + FBPK_OFF;
  uint32_t* idxF = keysF + fbcap;

  int mb = 0;
  hipOccupancyMaxActiveBlocksPerMultiprocessor(&mb, k_kwta, TPB, 0);
  if (mb < 1) mb = 1;
  int grid = mb * 256;  // 256 CUs on MI355X
  if (grid > MAXNB) grid = MAXNB;

  const float4* in4 = (const float4*)in;
  float4* out4 = (float4*)out;
  uint32_t n_u = (uint32_t)n;
  void* args[] = {(void*)&in4, (void*)&out4, (void*)&n4, (void*)&ntail,
                  (void*)&in, (void*)&out, (void*)&kptr, (void*)&n_u,
                  (void*)&ws, (void*)&keysR, (void*)&idxR,
                  (void*)&keysF, (void*)&idxF, (void*)&fbcap};
  hipLaunchCooperativeKernel((void*)k_kwta, dim3(grid), dim3(TPB), args, 0,
                             stream);
}